// Round 1
// baseline (6413.292 us; speedup 1.0000x reference)
//
#include <hip/hip_runtime.h>
#include <cstdint>
#include <cstddef>

#define NN 5000     // nodes per batch block
#define EE 40000    // edges per batch block
#define BATCH 8
#define SS 12
#define FF 16
#define HH 128
#define TOTAL 40000 // BATCH*NN
#define CC 4

// ---------------- graph preprocessing (once per launch) ----------------

__global__ void deg_cnt_kernel(const int* __restrict__ ei, const float* __restrict__ ew,
                               float* __restrict__ deg, int* __restrict__ cnt) {
  int e = blockIdx.x * 256 + threadIdx.x;
  if (e < EE) {
    int col = ei[EE + e];
    atomicAdd(&deg[col], ew[e]);
    atomicAdd(&cnt[col], 1);
  }
}

__global__ void dis_kernel(const float* __restrict__ deg, float* __restrict__ dis) {
  int n = blockIdx.x * 256 + threadIdx.x;
  if (n < NN) dis[n] = rsqrtf(deg[n] + 1.0f);  // +1: self-loop weight
}

// single-block exclusive scan of cnt[0..NN-1] -> offs[0..NN]
__global__ void scan_kernel(const int* __restrict__ cnt, int* __restrict__ offs) {
  __shared__ int part[256];
  const int CH = (NN + 255) / 256; // 20
  int tid = threadIdx.x;
  int base = tid * CH;
  int s = 0;
  for (int i = 0; i < CH; i++) { int idx = base + i; if (idx < NN) s += cnt[idx]; }
  part[tid] = s;
  __syncthreads();
  for (int off = 1; off < 256; off <<= 1) {
    int v = (tid >= off) ? part[tid - off] : 0;
    __syncthreads();
    part[tid] += v;
    __syncthreads();
  }
  int run = (tid == 0) ? 0 : part[tid - 1];
  for (int i = 0; i < CH; i++) {
    int idx = base + i;
    if (idx < NN) { offs[idx] = run; run += cnt[idx]; }
  }
  if (tid == 255) offs[NN] = run;
}

__global__ void fill_csr_kernel(const int* __restrict__ ei, const float* __restrict__ ew,
                                const float* __restrict__ dis, const int* __restrict__ offs,
                                int* __restrict__ cursor, int* __restrict__ csr_src,
                                float* __restrict__ csr_w) {
  int e = blockIdx.x * 256 + threadIdx.x;
  if (e < EE) {
    int row = ei[e], col = ei[EE + e];
    int pos = offs[col] + atomicAdd(&cursor[col], 1);
    csr_src[pos] = row;
    csr_w[pos] = dis[row] * ew[e] * dis[col];
  }
}

// ---------------- lin_in: xt = relu(x_t @ Win + bin) ----------------

__global__ __launch_bounds__(256) void lin_in_kernel(const float* __restrict__ x_seq,
                                                     const float* __restrict__ W,
                                                     const float* __restrict__ b,
                                                     float* __restrict__ xt, int t) {
  __shared__ float Ws[FF * HH]; // 8KB
  for (int k = threadIdx.x; k < FF * HH; k += 256) Ws[k] = W[k];
  __syncthreads();
  int idx = blockIdx.x * 256 + threadIdx.x; // over TOTAL*HH, exact cover
  int i = idx >> 7, h = idx & 127;
  int bb = i / NN, n = i - bb * NN;
  const float* xp = x_seq + (((size_t)bb * SS + t) * NN + n) * FF;
  float acc = b[h];
#pragma unroll
  for (int f = 0; f < FF; f++) acc += xp[f] * Ws[f * HH + h];
  xt[idx] = fmaxf(acc, 0.0f);
}

// ---------------- tiled fp32 GEMM ----------------
// C[M=40000, NC=NG*128] = concat(A1, A2*(R?)) @ W,  K=256 (A1 rows 0..127, A2 rows 128..255)
// W layout: Wbase + gate*(256*128), W[k*128 + j]
template <int NG, bool USE_R>
__global__ __launch_bounds__(256) void gemm_kernel(const float* __restrict__ A1,
                                                   const float* __restrict__ A2,
                                                   const float* __restrict__ R,
                                                   const float* __restrict__ Wbase,
                                                   float* __restrict__ out) {
  __shared__ float As[16][72];
  __shared__ float Bs[16][72];
  const int NC = NG * HH;
  int rowBase = blockIdx.x * 64;
  int colBase = blockIdx.y * 64;
  const float* Wp = Wbase + (size_t)(colBase >> 7) * (256 * HH);
  int jb = colBase & 127;
  int tid = threadIdx.x;
  int tx = tid & 15, ty = tid >> 4;
  int lr = tid >> 2;          // A-load row 0..63
  int lk4 = (tid & 3) << 2;   // A-load k offset
  int bk = tid >> 4;          // B-load k 0..15
  int bj4 = (tid & 15) << 2;  // B-load col offset
  float acc[4][4] = {{0.f}};
  for (int kc = 0; kc < 16; kc++) {
    int k0 = kc << 4;
    float4 av;
    if (kc < 8) {
      av = *(const float4*)(A1 + (size_t)(rowBase + lr) * HH + k0 + lk4);
    } else {
      size_t o = (size_t)(rowBase + lr) * HH + (k0 - 128) + lk4;
      av = *(const float4*)(A2 + o);
      if (USE_R) {
        float4 rv = *(const float4*)(R + o);
        av.x *= rv.x; av.y *= rv.y; av.z *= rv.z; av.w *= rv.w;
      }
    }
    float4 bv = *(const float4*)(Wp + (size_t)(k0 + bk) * HH + jb + bj4);
    __syncthreads(); // prior chunk's reads done before overwrite
    As[lk4 + 0][lr] = av.x; As[lk4 + 1][lr] = av.y;
    As[lk4 + 2][lr] = av.z; As[lk4 + 3][lr] = av.w;
    Bs[bk][bj4 + 0] = bv.x; Bs[bk][bj4 + 1] = bv.y;
    Bs[bk][bj4 + 2] = bv.z; Bs[bk][bj4 + 3] = bv.w;
    __syncthreads();
#pragma unroll
    for (int kk = 0; kk < 16; kk++) {
      float a[4], b[4];
      *(float4*)a = *(const float4*)&As[kk][ty << 2];
      *(float4*)b = *(const float4*)&Bs[kk][tx << 2];
#pragma unroll
      for (int i = 0; i < 4; i++)
#pragma unroll
        for (int j = 0; j < 4; j++) acc[i][j] += a[i] * b[j];
    }
  }
#pragma unroll
  for (int i = 0; i < 4; i++) {
    int rI = rowBase + (ty << 2) + i;
    float4 v = make_float4(acc[i][0], acc[i][1], acc[i][2], acc[i][3]);
    *(float4*)(out + (size_t)rI * NC + colBase + (tx << 2)) = v;
  }
}

// ---------------- scatter (aggregate by destination) + activation ----------------

__global__ __launch_bounds__(256) void scatter_gates_kernel(
    const float* __restrict__ G, const int* __restrict__ offs,
    const int* __restrict__ csr_src, const float* __restrict__ csr_w,
    const float* __restrict__ dis, const float* __restrict__ biasR,
    const float* __restrict__ biasU, float* __restrict__ r, float* __restrict__ u) {
  int i = blockIdx.x;                 // dest node
  int bb = i / NN;
  int n = i - bb * NN;
  int j = threadIdx.x;                // feature 0..255 (r|u)
  float sn = dis[n]; sn *= sn;        // self-loop norm = dis^2
  float acc = sn * G[(size_t)i * 256 + j];
  int e0 = offs[n], e1 = offs[n + 1];
  int base = bb * NN;
  for (int e = e0; e < e1; e++) {
    int src = base + csr_src[e];
    acc += csr_w[e] * G[(size_t)src * 256 + j];
  }
  if (j < HH) {
    float v = acc + biasR[j];
    r[(size_t)i * HH + j] = 1.0f / (1.0f + __expf(-v));
  } else {
    float v = acc + biasU[j - HH];
    u[(size_t)i * HH + (j - HH)] = 1.0f / (1.0f + __expf(-v));
  }
}

__global__ __launch_bounds__(128) void scatter_c_kernel(
    const float* __restrict__ Cpre, const int* __restrict__ offs,
    const int* __restrict__ csr_src, const float* __restrict__ csr_w,
    const float* __restrict__ dis, const float* __restrict__ biasC,
    float* __restrict__ c) {
  int i = blockIdx.x;
  int bb = i / NN;
  int n = i - bb * NN;
  int j = threadIdx.x;
  float sn = dis[n]; sn *= sn;
  float acc = sn * Cpre[(size_t)i * HH + j];
  int e0 = offs[n], e1 = offs[n + 1];
  int base = bb * NN;
  for (int e = e0; e < e1; e++) {
    int src = base + csr_src[e];
    acc += csr_w[e] * Cpre[(size_t)src * HH + j];
  }
  float v = acc + biasC[j];
  float ex = __expf(2.0f * v);
  c[(size_t)i * HH + j] = 1.0f - 2.0f / (ex + 1.0f); // tanh
}

// ---------------- GRU update: h = u*h + (1-u)*c ----------------

__global__ __launch_bounds__(256) void update_h_kernel(const float* __restrict__ u,
                                                       const float* __restrict__ c,
                                                       float* __restrict__ h) {
  int idx = blockIdx.x * 256 + threadIdx.x; // exact cover TOTAL*HH
  float uu = u[idx];
  h[idx] = uu * h[idx] + (1.0f - uu) * c[idx];
}

// ---------------- BatchNorm stats: sums[0:128]=sum, sums[128:256]=sumsq ----------------

__global__ __launch_bounds__(256) void bn_stats_kernel(const float* __restrict__ h,
                                                       float* __restrict__ sums) {
  __shared__ float ls[512];
  int tid = threadIdx.x;
  float s = 0.f, sq = 0.f;
  for (size_t idx = (size_t)blockIdx.x * 256 + tid; idx < (size_t)TOTAL * HH;
       idx += (size_t)gridDim.x * 256) {
    float v = h[idx];
    s += v; sq += v * v;
  }
  // stride multiple of 128 -> this thread always touches feature tid&127
  ls[tid] = s; ls[256 + tid] = sq;
  __syncthreads();
  if (tid < 128) {
    atomicAdd(&sums[tid], ls[tid] + ls[tid + 128]);
    atomicAdd(&sums[128 + tid], ls[256 + tid] + ls[256 + tid + 128]);
  }
}

// ---------------- fused BN -> relu -> lin_out -> log_softmax ----------------

__global__ __launch_bounds__(256) void final_kernel(const float* __restrict__ h,
                                                    const float* __restrict__ sums,
                                                    const float* __restrict__ gamma,
                                                    const float* __restrict__ beta,
                                                    const float* __restrict__ Wout,
                                                    const float* __restrict__ bout,
                                                    float* __restrict__ out) {
  int wid = threadIdx.x >> 6, lane = threadIdx.x & 63;
  int i = blockIdx.x * 4 + wid; // one wave per node
  if (i >= TOTAL) return;
  const float inv = 1.0f / (float)TOTAL;
  float p0 = 0.f, p1 = 0.f, p2 = 0.f, p3 = 0.f;
#pragma unroll
  for (int jj = 0; jj < 2; jj++) {
    int j = lane + jj * 64;
    float mean = sums[j] * inv;
    float var = sums[128 + j] * inv - mean * mean;
    float hn = (h[(size_t)i * HH + j] - mean) * rsqrtf(var + 1e-5f) * gamma[j] + beta[j];
    hn = fmaxf(hn, 0.0f);
    p0 += hn * Wout[j * 4 + 0];
    p1 += hn * Wout[j * 4 + 1];
    p2 += hn * Wout[j * 4 + 2];
    p3 += hn * Wout[j * 4 + 3];
  }
  for (int off = 32; off; off >>= 1) {
    p0 += __shfl_down(p0, off);
    p1 += __shfl_down(p1, off);
    p2 += __shfl_down(p2, off);
    p3 += __shfl_down(p3, off);
  }
  if (lane == 0) {
    p0 += bout[0]; p1 += bout[1]; p2 += bout[2]; p3 += bout[3];
    float m = fmaxf(fmaxf(p0, p1), fmaxf(p2, p3));
    float e = __expf(p0 - m) + __expf(p1 - m) + __expf(p2 - m) + __expf(p3 - m);
    float lse = m + __logf(e);
    float* o = out + (size_t)i * 4;
    o[0] = p0 - lse; o[1] = p1 - lse; o[2] = p2 - lse; o[3] = p3 - lse;
  }
}

// ---------------- launcher ----------------

extern "C" void kernel_launch(void* const* d_in, const int* in_sizes, int n_in,
                              void* d_out, int out_size, void* d_ws, size_t ws_size,
                              hipStream_t stream) {
  const float* x_seq = (const float*)d_in[0];
  const int* ei      = (const int*)d_in[1];
  const float* ew    = (const float*)d_in[2];
  const float* Win   = (const float*)d_in[3];
  const float* bin   = (const float*)d_in[4];
  const float* convW = (const float*)d_in[5];
  const float* convB = (const float*)d_in[6];
  const float* gamma = (const float*)d_in[7];
  const float* beta  = (const float*)d_in[8];
  const float* Wout  = (const float*)d_in[9];
  const float* bout  = (const float*)d_in[10];
  float* out = (float*)d_out;

  char* ws = (char*)d_ws;
  size_t off = 0;
  auto alloc = [&](size_t bytes) {
    void* p = ws + off;
    off += (bytes + 1023) & ~(size_t)1023;
    return p;
  };
  float* deg     = (float*)alloc(NN * 4);
  float* dis     = (float*)alloc(NN * 4);
  int*   cnt     = (int*)alloc(NN * 4);
  int*   offs    = (int*)alloc((NN + 1) * 4);
  int*   cursor  = (int*)alloc(NN * 4);
  int*   csr_src = (int*)alloc(EE * 4);
  float* csr_w   = (float*)alloc(EE * 4);
  float* sums    = (float*)alloc(256 * 4);
  const size_t NH = (size_t)TOTAL * HH; // 5,120,000
  float* h0 = (float*)alloc(NH * 4);
  float* h1 = (float*)alloc(NH * 4);
  float* xt = (float*)alloc(NH * 4);
  float* rb = (float*)alloc(NH * 4);
  float* ub = (float*)alloc(NH * 4);
  float* G  = (float*)alloc((size_t)TOTAL * 256 * 4); // gates pre-scatter; reused as Cpre|c
  float* Cpre = G;
  float* cb   = G + NH;

  // zero init
  hipMemsetAsync(deg, 0, NN * 4, stream);
  hipMemsetAsync(cnt, 0, NN * 4, stream);
  hipMemsetAsync(cursor, 0, NN * 4, stream);
  hipMemsetAsync(sums, 0, 256 * 4, stream);
  hipMemsetAsync(h0, 0, NH * 4, stream);
  hipMemsetAsync(h1, 0, NH * 4, stream);

  // graph preprocessing
  deg_cnt_kernel<<<(EE + 255) / 256, 256, 0, stream>>>(ei, ew, deg, cnt);
  dis_kernel<<<(NN + 255) / 256, 256, 0, stream>>>(deg, dis);
  scan_kernel<<<1, 256, 0, stream>>>(cnt, offs);
  fill_csr_kernel<<<(EE + 255) / 256, 256, 0, stream>>>(ei, ew, dis, offs, cursor, csr_src, csr_w);

  const size_t Wl = 3 * 256 * HH; // per-layer conv weights
  dim3 gGates(TOTAL / 64, 4), gC(TOTAL / 64, 2);

  for (int t = 0; t < SS; t++) {
    lin_in_kernel<<<TOTAL * HH / 256, 256, 0, stream>>>(x_seq, Win, bin, xt, t);
    for (int l = 0; l < 2; l++) {
      const float* xin = (l == 0) ? xt : h0;
      float* h = (l == 0) ? h0 : h1;
      const float* Wg = convW + (size_t)l * Wl;            // gate0 (r), gate1 (u) contiguous
      const float* Wc = convW + (size_t)l * Wl + 2 * 256 * HH;
      const float* bR = convB + (size_t)l * 3 * HH;
      const float* bU = bR + HH;
      const float* bC = bR + 2 * HH;
      gemm_kernel<2, false><<<gGates, 256, 0, stream>>>(xin, h, nullptr, Wg, G);
      scatter_gates_kernel<<<TOTAL, 256, 0, stream>>>(G, offs, csr_src, csr_w, dis, bR, bU, rb, ub);
      gemm_kernel<1, true><<<gC, 256, 0, stream>>>(xin, h, rb, Wc, Cpre);
      scatter_c_kernel<<<TOTAL, 128, 0, stream>>>(Cpre, offs, csr_src, csr_w, dis, bC, cb);
      update_h_kernel<<<TOTAL * HH / 256, 256, 0, stream>>>(ub, cb, h);
    }
  }

  bn_stats_kernel<<<256, 256, 0, stream>>>(h1, sums);
  final_kernel<<<TOTAL / 4, 256, 0, stream>>>(h1, sums, gamma, beta, Wout, bout, out);
}

// Round 2
// 2351.248 us; speedup vs baseline: 2.7276x; 2.7276x over previous
//
#include <hip/hip_runtime.h>
#include <cstdint>
#include <cstddef>

#define NN 5000     // nodes per batch block
#define EE 40000    // edges per batch block
#define BATCH 8
#define SS 12
#define FF 16
#define HH 128
#define TOTAL 40000 // BATCH*NN
#define CC 4

typedef __attribute__((ext_vector_type(8))) short short8;   // 8 bf16 (4 VGPRs)
typedef __attribute__((ext_vector_type(4))) float f32x4;    // 4 fp32

__device__ __forceinline__ unsigned short f2bf(float f) {
  union { float f; unsigned u; } v; v.f = f;
  unsigned r = v.u + 0x7fff + ((v.u >> 16) & 1);  // RTNE
  return (unsigned short)(r >> 16);
}
__device__ __forceinline__ float bf2f(unsigned short b) {
  union { unsigned u; float f; } v; v.u = ((unsigned)b) << 16;
  return v.f;
}

// ---------------- graph preprocessing (once per launch) ----------------

__global__ void deg_cnt_kernel(const int* __restrict__ ei, const float* __restrict__ ew,
                               float* __restrict__ deg, int* __restrict__ cnt) {
  int e = blockIdx.x * 256 + threadIdx.x;
  if (e < EE) {
    int col = ei[EE + e];
    atomicAdd(&deg[col], ew[e]);
    atomicAdd(&cnt[col], 1);
  }
}

__global__ void dis_kernel(const float* __restrict__ deg, float* __restrict__ dis) {
  int n = blockIdx.x * 256 + threadIdx.x;
  if (n < NN) dis[n] = rsqrtf(deg[n] + 1.0f);  // +1: self-loop weight
}

__global__ void scan_kernel(const int* __restrict__ cnt, int* __restrict__ offs) {
  __shared__ int part[256];
  const int CH = (NN + 255) / 256; // 20
  int tid = threadIdx.x;
  int base = tid * CH;
  int s = 0;
  for (int i = 0; i < CH; i++) { int idx = base + i; if (idx < NN) s += cnt[idx]; }
  part[tid] = s;
  __syncthreads();
  for (int off = 1; off < 256; off <<= 1) {
    int v = (tid >= off) ? part[tid - off] : 0;
    __syncthreads();
    part[tid] += v;
    __syncthreads();
  }
  int run = (tid == 0) ? 0 : part[tid - 1];
  for (int i = 0; i < CH; i++) {
    int idx = base + i;
    if (idx < NN) { offs[idx] = run; run += cnt[idx]; }
  }
  if (tid == 255) offs[NN] = run;
}

__global__ void fill_csr_kernel(const int* __restrict__ ei, const float* __restrict__ ew,
                                const float* __restrict__ dis, const int* __restrict__ offs,
                                int* __restrict__ cursor, int* __restrict__ csr_src,
                                float* __restrict__ csr_w) {
  int e = blockIdx.x * 256 + threadIdx.x;
  if (e < EE) {
    int row = ei[e], col = ei[EE + e];
    int pos = offs[col] + atomicAdd(&cursor[col], 1);
    csr_src[pos] = row;
    csr_w[pos] = dis[row] * ew[e] * dis[col];
  }
}

// ---------------- weight prepack: fp32 [k][n] -> bf16 MFMA b-frag order ----------------
// packed[g][nt][ks][lane][8]: lane holds B[k=ks*32+(lane>>4)*8+j][n=nt*16+(lane&15)]
// g = matrix index 0..5 (layer*3 + gate), each 256x128.

__global__ void prepack_kernel(const float* __restrict__ convW, unsigned short* __restrict__ Wp) {
  int idx = blockIdx.x * 256 + threadIdx.x;  // 6*8*8*64 = 24576
  int lane = idx & 63;
  int ks = (idx >> 6) & 7;
  int nt = (idx >> 9) & 7;
  int g = idx >> 12;
  const float* W = convW + (size_t)g * 256 * 128;
  int n = nt * 16 + (lane & 15);
  int k0 = ks * 32 + (lane >> 4) * 8;
  unsigned short v[8];
#pragma unroll
  for (int j = 0; j < 8; j++) v[j] = f2bf(W[(size_t)(k0 + j) * 128 + n]);
  *(uint4*)(Wp + (size_t)idx * 8) = *(const uint4*)v;
}

// ---------------- lin_in: xt = relu(x_t @ Win + bin), bf16 out, row = n*8+bb ----------------

__global__ __launch_bounds__(256) void lin_in_kernel(const float* __restrict__ x_seq,
                                                     const float* __restrict__ W,
                                                     const float* __restrict__ b,
                                                     unsigned short* __restrict__ xt, int t) {
  __shared__ float Ws[FF * HH]; // 8KB
  for (int k = threadIdx.x; k < FF * HH; k += 256) Ws[k] = W[k];
  __syncthreads();
  int idx = blockIdx.x * 256 + threadIdx.x; // over TOTAL*HH, exact cover
  int row = idx >> 7, f = idx & 127;
  int n = row >> 3, bb = row & 7;
  const float* xp = x_seq + (((size_t)bb * SS + t) * NN + n) * FF;
  float acc = b[f];
#pragma unroll
  for (int ff = 0; ff < FF; ff++) acc += xp[ff] * Ws[ff * HH + f];
  xt[idx] = f2bf(fmaxf(acc, 0.0f));
}

// ---------------- bf16 MFMA GEMM ----------------
// out[M=40000, N=NTW*64] = concat(A1, A2) @ Wpacked, K=256, all bf16, fp32 accum.
// NTW = n-tiles(16 cols) per wave; 4 waves cover N = NTW*4*16.

template <int NTW>
__global__ __launch_bounds__(256) void gemm_mfma(const unsigned short* __restrict__ A1,
                                                 const unsigned short* __restrict__ A2,
                                                 const unsigned short* __restrict__ Wp,
                                                 unsigned short* __restrict__ out) {
  constexpr int N = NTW * 4 * 16;
  __shared__ unsigned short As[64 * 264];  // 64 rows x 256 K, +8 pad
  int rowBase = blockIdx.x * 64;
  int tid = threadIdx.x;
  // stage A (already bf16): 2048 chunks of 16B, 8 per thread
  for (int c = tid; c < 2048; c += 256) {
    int row = c >> 5; int rest = c & 31; int half = rest >> 4; int sub = rest & 15;
    const unsigned short* src = (half ? A2 : A1) + ((size_t)(rowBase + row) * 128 + sub * 8);
    *(uint4*)&As[row * 264 + half * 128 + sub * 8] = *(const uint4*)src;
  }
  __syncthreads();
  int wv = tid >> 6, lane = tid & 63;
  int m = lane & 15, q = lane >> 4;
  f32x4 acc[4][NTW];
#pragma unroll
  for (int i = 0; i < 4; i++)
#pragma unroll
    for (int j = 0; j < NTW; j++) acc[i][j] = (f32x4)(0.0f);
  const unsigned short* wbase = Wp + ((size_t)(wv * NTW) * 8 * 64 + lane) * 8;
#pragma unroll
  for (int ks = 0; ks < 8; ks++) {
    short8 a[4];
#pragma unroll
    for (int mt = 0; mt < 4; mt++)
      a[mt] = *(const short8*)&As[(mt * 16 + m) * 264 + ks * 32 + q * 8];
#pragma unroll
    for (int nt = 0; nt < NTW; nt++) {
      short8 b = *(const short8*)(wbase + (size_t)(nt * 8 + ks) * 64 * 8);
#pragma unroll
      for (int mt = 0; mt < 4; mt++)
        acc[mt][nt] = __builtin_amdgcn_mfma_f32_16x16x32_bf16(a[mt], b, acc[mt][nt], 0, 0, 0);
    }
  }
#pragma unroll
  for (int mt = 0; mt < 4; mt++)
#pragma unroll
    for (int nt = 0; nt < NTW; nt++) {
      int col = (wv * NTW + nt) * 16 + m;
#pragma unroll
      for (int i = 0; i < 4; i++) {
        int row = rowBase + mt * 16 + q * 4 + i;
        out[(size_t)row * N + col] = f2bf(acc[mt][nt][i]);
      }
    }
}

// ---------------- scatter gates: aggregate G -> r,u; write rh = r*h, u ----------------

__global__ __launch_bounds__(256) void scatter_gates_kernel(
    const unsigned short* __restrict__ G, const int* __restrict__ offs,
    const int* __restrict__ csr_src, const float* __restrict__ csr_w,
    const float* __restrict__ dis, const float* __restrict__ bRU,
    const unsigned short* __restrict__ h, unsigned short* __restrict__ rh,
    unsigned short* __restrict__ u) {
  int n = blockIdx.x;
  int f = threadIdx.x;  // 0..255 (r|u feature)
  float sn = dis[n]; sn *= sn;
  float acc[8];
  const unsigned short* Gn = G + ((size_t)(n << 3)) * 256 + f;
#pragma unroll
  for (int bb = 0; bb < 8; bb++) acc[bb] = sn * bf2f(Gn[(size_t)bb * 256]);
  int e0 = offs[n], e1 = offs[n + 1];
  for (int e = e0; e < e1; e++) {
    int s = csr_src[e];
    float w = csr_w[e];
    const unsigned short* Gs = G + ((size_t)(s << 3)) * 256 + f;
#pragma unroll
    for (int bb = 0; bb < 8; bb++) acc[bb] += w * bf2f(Gs[(size_t)bb * 256]);
  }
  float bias = bRU[f];
  if (f < 128) {
#pragma unroll
    for (int bb = 0; bb < 8; bb++) {
      float r = 1.0f / (1.0f + __expf(-(acc[bb] + bias)));
      size_t row = (size_t)(n << 3) + bb;
      rh[row * 128 + f] = f2bf(r * bf2f(h[row * 128 + f]));
    }
  } else {
    int fu = f - 128;
#pragma unroll
    for (int bb = 0; bb < 8; bb++) {
      float uu = 1.0f / (1.0f + __expf(-(acc[bb] + bias)));
      u[((size_t)(n << 3) + bb) * 128 + fu] = f2bf(uu);
    }
  }
}

// ---------------- scatter candidate + GRU update: h = u*h + (1-u)*tanh(agg+bC) ----------------

__global__ __launch_bounds__(256) void scatter_c_update_kernel(
    const unsigned short* __restrict__ Cp, const int* __restrict__ offs,
    const int* __restrict__ csr_src, const float* __restrict__ csr_w,
    const float* __restrict__ dis, const float* __restrict__ bC,
    const unsigned short* __restrict__ u, unsigned short* __restrict__ h) {
  int n = blockIdx.x;
  int f = threadIdx.x & 127;
  int bg = (threadIdx.x >> 7) * 4;  // batch group: 0..3 or 4..7
  float sn = dis[n]; sn *= sn;
  float acc[4];
  const unsigned short* Cn = Cp + ((size_t)(n << 3) + bg) * 128 + f;
#pragma unroll
  for (int bb = 0; bb < 4; bb++) acc[bb] = sn * bf2f(Cn[(size_t)bb * 128]);
  int e0 = offs[n], e1 = offs[n + 1];
  for (int e = e0; e < e1; e++) {
    int s = csr_src[e];
    float w = csr_w[e];
    const unsigned short* Cs = Cp + ((size_t)(s << 3) + bg) * 128 + f;
#pragma unroll
    for (int bb = 0; bb < 4; bb++) acc[bb] += w * bf2f(Cs[(size_t)bb * 128]);
  }
  float bias = bC[f];
#pragma unroll
  for (int bb = 0; bb < 4; bb++) {
    float v = acc[bb] + bias;
    float ex = __expf(2.0f * v);
    float c = 1.0f - 2.0f / (ex + 1.0f);  // tanh
    size_t row = (size_t)(n << 3) + bg + bb;
    float uu = bf2f(u[row * 128 + f]);
    float hv = bf2f(h[row * 128 + f]);
    h[row * 128 + f] = f2bf(uu * hv + (1.0f - uu) * c);
  }
}

// ---------------- BatchNorm stats: sums[0:128]=sum, sums[128:256]=sumsq ----------------

__global__ __launch_bounds__(256) void bn_stats_kernel(const unsigned short* __restrict__ h,
                                                       float* __restrict__ sums) {
  __shared__ float ls[512];
  int tid = threadIdx.x;
  float s = 0.f, sq = 0.f;
  for (size_t idx = (size_t)blockIdx.x * 256 + tid; idx < (size_t)TOTAL * HH;
       idx += (size_t)gridDim.x * 256) {
    float v = bf2f(h[idx]);
    s += v; sq += v * v;
  }
  ls[tid] = s; ls[256 + tid] = sq;
  __syncthreads();
  if (tid < 128) {
    atomicAdd(&sums[tid], ls[tid] + ls[tid + 128]);
    atomicAdd(&sums[128 + tid], ls[256 + tid] + ls[256 + tid + 128]);
  }
}

// ---------------- fused BN -> relu -> lin_out -> log_softmax ----------------

__global__ __launch_bounds__(256) void final_kernel(const unsigned short* __restrict__ h,
                                                    const float* __restrict__ sums,
                                                    const float* __restrict__ gamma,
                                                    const float* __restrict__ beta,
                                                    const float* __restrict__ Wout,
                                                    const float* __restrict__ bout,
                                                    float* __restrict__ out) {
  int wid = threadIdx.x >> 6, lane = threadIdx.x & 63;
  int row = blockIdx.x * 4 + wid; // one wave per node-row (n*8+bb order)
  if (row >= TOTAL) return;
  const float inv = 1.0f / (float)TOTAL;
  float p0 = 0.f, p1 = 0.f, p2 = 0.f, p3 = 0.f;
#pragma unroll
  for (int jj = 0; jj < 2; jj++) {
    int j = lane + jj * 64;
    float mean = sums[j] * inv;
    float var = sums[128 + j] * inv - mean * mean;
    float hn = (bf2f(h[(size_t)row * HH + j]) - mean) * rsqrtf(var + 1e-5f) * gamma[j] + beta[j];
    hn = fmaxf(hn, 0.0f);
    p0 += hn * Wout[j * 4 + 0];
    p1 += hn * Wout[j * 4 + 1];
    p2 += hn * Wout[j * 4 + 2];
    p3 += hn * Wout[j * 4 + 3];
  }
  for (int off = 32; off; off >>= 1) {
    p0 += __shfl_down(p0, off);
    p1 += __shfl_down(p1, off);
    p2 += __shfl_down(p2, off);
    p3 += __shfl_down(p3, off);
  }
  if (lane == 0) {
    p0 += bout[0]; p1 += bout[1]; p2 += bout[2]; p3 += bout[3];
    float m = fmaxf(fmaxf(p0, p1), fmaxf(p2, p3));
    float e = __expf(p0 - m) + __expf(p1 - m) + __expf(p2 - m) + __expf(p3 - m);
    float lse = m + __logf(e);
    int bb = row & 7, n = row >> 3;
    float* o = out + ((size_t)bb * NN + n) * 4;
    o[0] = p0 - lse; o[1] = p1 - lse; o[2] = p2 - lse; o[3] = p3 - lse;
  }
}

// ---------------- launcher ----------------

extern "C" void kernel_launch(void* const* d_in, const int* in_sizes, int n_in,
                              void* d_out, int out_size, void* d_ws, size_t ws_size,
                              hipStream_t stream) {
  const float* x_seq = (const float*)d_in[0];
  const int* ei      = (const int*)d_in[1];
  const float* ew    = (const float*)d_in[2];
  const float* Win   = (const float*)d_in[3];
  const float* bin   = (const float*)d_in[4];
  const float* convW = (const float*)d_in[5];
  const float* convB = (const float*)d_in[6];
  const float* gamma = (const float*)d_in[7];
  const float* beta  = (const float*)d_in[8];
  const float* Wout  = (const float*)d_in[9];
  const float* bout  = (const float*)d_in[10];
  float* out = (float*)d_out;

  char* ws = (char*)d_ws;
  size_t off = 0;
  auto alloc = [&](size_t bytes) {
    void* p = ws + off;
    off += (bytes + 1023) & ~(size_t)1023;
    return p;
  };
  float* deg     = (float*)alloc(NN * 4);
  float* dis     = (float*)alloc(NN * 4);
  int*   cnt     = (int*)alloc(NN * 4);
  int*   offs    = (int*)alloc((NN + 1) * 4);
  int*   cursor  = (int*)alloc(NN * 4);
  int*   csr_src = (int*)alloc(EE * 4);
  float* csr_w   = (float*)alloc(EE * 4);
  float* sums    = (float*)alloc(256 * 4);
  unsigned short* Wp = (unsigned short*)alloc(6 * 32768 * 2);  // packed conv weights
  const size_t NH = (size_t)TOTAL * HH; // 5,120,000
  unsigned short* h0 = (unsigned short*)alloc(NH * 2);
  unsigned short* h1 = (unsigned short*)alloc(NH * 2);
  unsigned short* xt = (unsigned short*)alloc(NH * 2);
  unsigned short* rh = (unsigned short*)alloc(NH * 2);
  unsigned short* ub = (unsigned short*)alloc(NH * 2);
  unsigned short* G  = (unsigned short*)alloc((size_t)TOTAL * 256 * 2); // gates pre-scatter
  unsigned short* Cpre = G;  // candidate pre-scatter reuses G (TOTAL*128)

  hipMemsetAsync(deg, 0, NN * 4, stream);
  hipMemsetAsync(cnt, 0, NN * 4, stream);
  hipMemsetAsync(cursor, 0, NN * 4, stream);
  hipMemsetAsync(sums, 0, 256 * 4, stream);
  hipMemsetAsync(h0, 0, NH * 2, stream);
  hipMemsetAsync(h1, 0, NH * 2, stream);

  deg_cnt_kernel<<<(EE + 255) / 256, 256, 0, stream>>>(ei, ew, deg, cnt);
  dis_kernel<<<(NN + 255) / 256, 256, 0, stream>>>(deg, dis);
  scan_kernel<<<1, 256, 0, stream>>>(cnt, offs);
  fill_csr_kernel<<<(EE + 255) / 256, 256, 0, stream>>>(ei, ew, dis, offs, cursor, csr_src, csr_w);
  prepack_kernel<<<24576 / 256, 256, 0, stream>>>(convW, Wp);

  for (int t = 0; t < SS; t++) {
    lin_in_kernel<<<TOTAL * HH / 256, 256, 0, stream>>>(x_seq, Win, bin, xt, t);
    for (int l = 0; l < 2; l++) {
      const unsigned short* xin = (l == 0) ? xt : h0;
      unsigned short* h = (l == 0) ? h0 : h1;
      const unsigned short* Wg = Wp + (size_t)(l * 3) * 32768;      // r|u packed, contiguous
      const unsigned short* Wc = Wp + (size_t)(l * 3 + 2) * 32768;
      const float* bRU = convB + (size_t)l * 3 * HH;
      const float* bC  = bRU + 2 * HH;
      gemm_mfma<4><<<TOTAL / 64, 256, 0, stream>>>(xin, h, Wg, G);
      scatter_gates_kernel<<<NN, 256, 0, stream>>>(G, offs, csr_src, csr_w, dis, bRU, h, rh, ub);
      gemm_mfma<2><<<TOTAL / 64, 256, 0, stream>>>(xin, rh, Wc, Cpre);
      scatter_c_update_kernel<<<NN, 256, 0, stream>>>(Cpre, offs, csr_src, csr_w, dis, bC, ub, h);
    }
  }

  bn_stats_kernel<<<256, 256, 0, stream>>>(h1, sums);
  final_kernel<<<TOTAL / 4, 256, 0, stream>>>(h1, sums, gamma, beta, Wout, bout, out);
}

// Round 3
// 2092.979 us; speedup vs baseline: 3.0642x; 1.1234x over previous
//
#include <hip/hip_runtime.h>
#include <cstdint>
#include <cstddef>

#define NN 5000     // nodes per batch block
#define EE 40000    // edges per batch block
#define BATCH 8
#define SS 12
#define FF 16
#define HH 128
#define TOTAL 40000 // BATCH*NN
#define CC 4

typedef __attribute__((ext_vector_type(8))) short short8;   // 8 bf16 (4 VGPRs)
typedef __attribute__((ext_vector_type(4))) float f32x4;    // 4 fp32

__device__ __forceinline__ unsigned short f2bf(float f) {
  union { float f; unsigned u; } v; v.f = f;
  unsigned r = v.u + 0x7fff + ((v.u >> 16) & 1);  // RTNE
  return (unsigned short)(r >> 16);
}
__device__ __forceinline__ float bf2f(unsigned short b) {
  union { unsigned u; float f; } v; v.u = ((unsigned)b) << 16;
  return v.f;
}
__device__ __forceinline__ float bflo(unsigned v) {
  union { unsigned u; float f; } x; x.u = v << 16; return x.f;
}
__device__ __forceinline__ float bfhi(unsigned v) {
  union { unsigned u; float f; } x; x.u = v & 0xffff0000u; return x.f;
}

// ---------------- graph preprocessing (once per launch) ----------------

__global__ void deg_cnt_kernel(const int* __restrict__ ei, const float* __restrict__ ew,
                               float* __restrict__ deg, int* __restrict__ cnt) {
  int e = blockIdx.x * 256 + threadIdx.x;
  if (e < EE) {
    int col = ei[EE + e];
    atomicAdd(&deg[col], ew[e]);
    atomicAdd(&cnt[col], 1);
  }
}

__global__ void dis_kernel(const float* __restrict__ deg, float* __restrict__ dis) {
  int n = blockIdx.x * 256 + threadIdx.x;
  if (n < NN) dis[n] = rsqrtf(deg[n] + 1.0f);  // +1: self-loop weight
}

__global__ void scan_kernel(const int* __restrict__ cnt, int* __restrict__ offs) {
  __shared__ int part[256];
  const int CH = (NN + 255) / 256; // 20
  int tid = threadIdx.x;
  int base = tid * CH;
  int s = 0;
  for (int i = 0; i < CH; i++) { int idx = base + i; if (idx < NN) s += cnt[idx]; }
  part[tid] = s;
  __syncthreads();
  for (int off = 1; off < 256; off <<= 1) {
    int v = (tid >= off) ? part[tid - off] : 0;
    __syncthreads();
    part[tid] += v;
    __syncthreads();
  }
  int run = (tid == 0) ? 0 : part[tid - 1];
  for (int i = 0; i < CH; i++) {
    int idx = base + i;
    if (idx < NN) { offs[idx] = run; run += cnt[idx]; }
  }
  if (tid == 255) offs[NN] = run;
}

__global__ void fill_csr_kernel(const int* __restrict__ ei, const float* __restrict__ ew,
                                const float* __restrict__ dis, const int* __restrict__ offs,
                                int* __restrict__ cursor, int* __restrict__ csr_src,
                                float* __restrict__ csr_w) {
  int e = blockIdx.x * 256 + threadIdx.x;
  if (e < EE) {
    int row = ei[e], col = ei[EE + e];
    int pos = offs[col] + atomicAdd(&cursor[col], 1);
    csr_src[pos] = row;
    csr_w[pos] = dis[row] * ew[e] * dis[col];
  }
}

// ---------------- weight prepack: fp32 [k][n] -> bf16 MFMA b-frag order ----------------
// packed[g][nt][ks][lane][8]: lane holds B[k=ks*32+(lane>>4)*8+j][n=nt*16+(lane&15)]

__global__ void prepack_kernel(const float* __restrict__ convW, unsigned short* __restrict__ Wp) {
  int idx = blockIdx.x * 256 + threadIdx.x;  // 6*8*8*64 = 24576
  int lane = idx & 63;
  int ks = (idx >> 6) & 7;
  int nt = (idx >> 9) & 7;
  int g = idx >> 12;
  const float* W = convW + (size_t)g * 256 * 128;
  int n = nt * 16 + (lane & 15);
  int k0 = ks * 32 + (lane >> 4) * 8;
  unsigned short v[8];
#pragma unroll
  for (int j = 0; j < 8; j++) v[j] = f2bf(W[(size_t)(k0 + j) * 128 + n]);
  *(uint4*)(Wp + (size_t)idx * 8) = *(const uint4*)v;
}

// ---------------- lin_in: xt = relu(x_t @ Win + bin), bf16 out, row = n*8+bb ----------------

__global__ __launch_bounds__(256) void lin_in_kernel(const float* __restrict__ x_seq,
                                                     const float* __restrict__ W,
                                                     const float* __restrict__ b,
                                                     unsigned short* __restrict__ xt, int t) {
  int idx = blockIdx.x * 256 + threadIdx.x;   // over TOTAL*32
  int row = idx >> 5, fq = idx & 31;          // feats 4fq..4fq+3
  int n = row >> 3, bb = row & 7;
  const float* xp = x_seq + (((size_t)bb * SS + t) * NN + n) * FF;
  float4 a = *(const float4*)&b[fq * 4];
#pragma unroll
  for (int ff = 0; ff < FF; ff++) {
    float xv = xp[ff];
    float4 w = *(const float4*)&W[ff * HH + fq * 4];
    a.x += xv * w.x; a.y += xv * w.y; a.z += xv * w.z; a.w += xv * w.w;
  }
  uint2 o;
  o.x = (unsigned)f2bf(fmaxf(a.x, 0.f)) | ((unsigned)f2bf(fmaxf(a.y, 0.f)) << 16);
  o.y = (unsigned)f2bf(fmaxf(a.z, 0.f)) | ((unsigned)f2bf(fmaxf(a.w, 0.f)) << 16);
  *(uint2*)&xt[(size_t)row * 128 + fq * 4] = o;
}

// ---------------- bf16 MFMA GEMM ----------------
// [M=40000, N=NTW*64] = concat(A1, A2) @ Wpacked, K=256, fp32 accum.
// Output split: col<128 -> outR[row*128+col], col>=128 -> outU[row*128+col-128].

template <int NTW>
__global__ __launch_bounds__(256) void gemm_mfma(const unsigned short* __restrict__ A1,
                                                 const unsigned short* __restrict__ A2,
                                                 const unsigned short* __restrict__ Wp,
                                                 unsigned short* __restrict__ outR,
                                                 unsigned short* __restrict__ outU) {
  __shared__ unsigned short As[64 * 264];  // 64 rows x 256 K, +8 pad
  int rowBase = blockIdx.x * 64;
  int tid = threadIdx.x;
  for (int c = tid; c < 2048; c += 256) {
    int row = c >> 5; int rest = c & 31; int half = rest >> 4; int sub = rest & 15;
    const unsigned short* src = (half ? A2 : A1) + ((size_t)(rowBase + row) * 128 + sub * 8);
    *(uint4*)&As[row * 264 + half * 128 + sub * 8] = *(const uint4*)src;
  }
  __syncthreads();
  int wv = tid >> 6, lane = tid & 63;
  int m = lane & 15, q = lane >> 4;
  f32x4 acc[4][NTW];
#pragma unroll
  for (int i = 0; i < 4; i++)
#pragma unroll
    for (int j = 0; j < NTW; j++) acc[i][j] = (f32x4)(0.0f);
  const unsigned short* wbase = Wp + ((size_t)(wv * NTW) * 8 * 64 + lane) * 8;
#pragma unroll
  for (int ks = 0; ks < 8; ks++) {
    short8 a[4];
#pragma unroll
    for (int mt = 0; mt < 4; mt++)
      a[mt] = *(const short8*)&As[(mt * 16 + m) * 264 + ks * 32 + q * 8];
#pragma unroll
    for (int nt = 0; nt < NTW; nt++) {
      short8 b = *(const short8*)(wbase + (size_t)(nt * 8 + ks) * 64 * 8);
#pragma unroll
      for (int mt = 0; mt < 4; mt++)
        acc[mt][nt] = __builtin_amdgcn_mfma_f32_16x16x32_bf16(a[mt], b, acc[mt][nt], 0, 0, 0);
    }
  }
#pragma unroll
  for (int mt = 0; mt < 4; mt++)
#pragma unroll
    for (int nt = 0; nt < NTW; nt++) {
      int col = (wv * NTW + nt) * 16 + m;
      unsigned short* op = (col < 128) ? (outR + col) : (outU + (col - 128));
#pragma unroll
      for (int i = 0; i < 4; i++) {
        int row = rowBase + mt * 16 + q * 4 + i;
        op[(size_t)row * 128] = f2bf(acc[mt][nt][i]);
      }
    }
}

// ---------------- gates aggregation: r|u halves, vectorized uint2 gather ----------------
// grid (NN, 2): y=0 -> r half (writes rh=r*h), y=1 -> u half (writes u).

__global__ __launch_bounds__(256) void scatter_gates_kernel(
    const unsigned short* __restrict__ GR, const unsigned short* __restrict__ GU,
    const int* __restrict__ offs, const int* __restrict__ csr_src,
    const float* __restrict__ csr_w, const float* __restrict__ dis,
    const float* __restrict__ bRU, const unsigned short* __restrict__ h,
    unsigned short* __restrict__ rh, unsigned short* __restrict__ u) {
  int n = blockIdx.x;
  int half = blockIdx.y;
  int fq = threadIdx.x & 31;   // feature quad 4fq..4fq+3
  int bb = threadIdx.x >> 5;   // batch 0..7
  const unsigned short* G = half ? GU : GR;
  float sn = dis[n]; sn *= sn;
  size_t rowSelf = (size_t)(n << 3) + bb;
  size_t fo = (size_t)fq * 4;
  uint2 g = *(const uint2*)&G[rowSelf * 128 + fo];
  float a0 = sn * bflo(g.x), a1 = sn * bfhi(g.x);
  float a2 = sn * bflo(g.y), a3 = sn * bfhi(g.y);
  int e0 = offs[n], e1 = offs[n + 1];
  int e = e0;
  for (; e + 1 < e1; e += 2) {
    int s0 = csr_src[e], s1 = csr_src[e + 1];
    float w0 = csr_w[e], w1 = csr_w[e + 1];
    uint2 ga = *(const uint2*)&G[(((size_t)s0 << 3) + bb) * 128 + fo];
    uint2 gb = *(const uint2*)&G[(((size_t)s1 << 3) + bb) * 128 + fo];
    a0 += w0 * bflo(ga.x); a1 += w0 * bfhi(ga.x);
    a2 += w0 * bflo(ga.y); a3 += w0 * bfhi(ga.y);
    a0 += w1 * bflo(gb.x); a1 += w1 * bfhi(gb.x);
    a2 += w1 * bflo(gb.y); a3 += w1 * bfhi(gb.y);
  }
  if (e < e1) {
    int s0 = csr_src[e];
    float w0 = csr_w[e];
    uint2 ga = *(const uint2*)&G[(((size_t)s0 << 3) + bb) * 128 + fo];
    a0 += w0 * bflo(ga.x); a1 += w0 * bfhi(ga.x);
    a2 += w0 * bflo(ga.y); a3 += w0 * bfhi(ga.y);
  }
  const float* bias = bRU + half * 128 + fo;
  float v0 = 1.0f / (1.0f + __expf(-(a0 + bias[0])));
  float v1 = 1.0f / (1.0f + __expf(-(a1 + bias[1])));
  float v2 = 1.0f / (1.0f + __expf(-(a2 + bias[2])));
  float v3 = 1.0f / (1.0f + __expf(-(a3 + bias[3])));
  if (half == 0) {
    uint2 hv = *(const uint2*)&h[rowSelf * 128 + fo];
    v0 *= bflo(hv.x); v1 *= bfhi(hv.x); v2 *= bflo(hv.y); v3 *= bfhi(hv.y);
    uint2 o;
    o.x = (unsigned)f2bf(v0) | ((unsigned)f2bf(v1) << 16);
    o.y = (unsigned)f2bf(v2) | ((unsigned)f2bf(v3) << 16);
    *(uint2*)&rh[rowSelf * 128 + fo] = o;
  } else {
    uint2 o;
    o.x = (unsigned)f2bf(v0) | ((unsigned)f2bf(v1) << 16);
    o.y = (unsigned)f2bf(v2) | ((unsigned)f2bf(v3) << 16);
    *(uint2*)&u[rowSelf * 128 + fo] = o;
  }
}

// ---------------- candidate aggregation + GRU update ----------------

__global__ __launch_bounds__(256) void scatter_c_update_kernel(
    const unsigned short* __restrict__ Cp, const int* __restrict__ offs,
    const int* __restrict__ csr_src, const float* __restrict__ csr_w,
    const float* __restrict__ dis, const float* __restrict__ bC,
    const unsigned short* __restrict__ u, unsigned short* __restrict__ h) {
  int n = blockIdx.x;
  int fq = threadIdx.x & 31;
  int bb = threadIdx.x >> 5;
  float sn = dis[n]; sn *= sn;
  size_t rowSelf = (size_t)(n << 3) + bb;
  size_t fo = (size_t)fq * 4;
  uint2 g = *(const uint2*)&Cp[rowSelf * 128 + fo];
  float a0 = sn * bflo(g.x), a1 = sn * bfhi(g.x);
  float a2 = sn * bflo(g.y), a3 = sn * bfhi(g.y);
  int e0 = offs[n], e1 = offs[n + 1];
  int e = e0;
  for (; e + 1 < e1; e += 2) {
    int s0 = csr_src[e], s1 = csr_src[e + 1];
    float w0 = csr_w[e], w1 = csr_w[e + 1];
    uint2 ga = *(const uint2*)&Cp[(((size_t)s0 << 3) + bb) * 128 + fo];
    uint2 gb = *(const uint2*)&Cp[(((size_t)s1 << 3) + bb) * 128 + fo];
    a0 += w0 * bflo(ga.x); a1 += w0 * bfhi(ga.x);
    a2 += w0 * bflo(ga.y); a3 += w0 * bfhi(ga.y);
    a0 += w1 * bflo(gb.x); a1 += w1 * bfhi(gb.x);
    a2 += w1 * bflo(gb.y); a3 += w1 * bfhi(gb.y);
  }
  if (e < e1) {
    int s0 = csr_src[e];
    float w0 = csr_w[e];
    uint2 ga = *(const uint2*)&Cp[(((size_t)s0 << 3) + bb) * 128 + fo];
    a0 += w0 * bflo(ga.x); a1 += w0 * bfhi(ga.x);
    a2 += w0 * bflo(ga.y); a3 += w0 * bfhi(ga.y);
  }
  const float* bp = bC + fo;
  float c0, c1, c2, c3;
  {
    float v;
    v = a0 + bp[0]; c0 = 1.0f - 2.0f / (__expf(2.0f * v) + 1.0f);
    v = a1 + bp[1]; c1 = 1.0f - 2.0f / (__expf(2.0f * v) + 1.0f);
    v = a2 + bp[2]; c2 = 1.0f - 2.0f / (__expf(2.0f * v) + 1.0f);
    v = a3 + bp[3]; c3 = 1.0f - 2.0f / (__expf(2.0f * v) + 1.0f);
  }
  uint2 uv = *(const uint2*)&u[rowSelf * 128 + fo];
  uint2 hv = *(const uint2*)&h[rowSelf * 128 + fo];
  float u0 = bflo(uv.x), u1 = bfhi(uv.x), u2 = bflo(uv.y), u3 = bfhi(uv.y);
  float h0 = bflo(hv.x), h1 = bfhi(hv.x), h2 = bflo(hv.y), h3 = bfhi(hv.y);
  float n0 = u0 * h0 + (1.0f - u0) * c0;
  float n1 = u1 * h1 + (1.0f - u1) * c1;
  float n2 = u2 * h2 + (1.0f - u2) * c2;
  float n3 = u3 * h3 + (1.0f - u3) * c3;
  uint2 o;
  o.x = (unsigned)f2bf(n0) | ((unsigned)f2bf(n1) << 16);
  o.y = (unsigned)f2bf(n2) | ((unsigned)f2bf(n3) << 16);
  *(uint2*)&h[rowSelf * 128 + fo] = o;
}

// ---------------- BatchNorm stats ----------------

__global__ __launch_bounds__(256) void bn_stats_kernel(const unsigned short* __restrict__ h,
                                                       float* __restrict__ sums) {
  __shared__ float ls[512];
  int tid = threadIdx.x;
  float s = 0.f, sq = 0.f;
  for (size_t idx = (size_t)blockIdx.x * 256 + tid; idx < (size_t)TOTAL * HH;
       idx += (size_t)gridDim.x * 256) {
    float v = bf2f(h[idx]);
    s += v; sq += v * v;
  }
  ls[tid] = s; ls[256 + tid] = sq;
  __syncthreads();
  if (tid < 128) {
    atomicAdd(&sums[tid], ls[tid] + ls[tid + 128]);
    atomicAdd(&sums[128 + tid], ls[256 + tid] + ls[256 + tid + 128]);
  }
}

// ---------------- fused BN -> relu -> lin_out -> log_softmax ----------------

__global__ __launch_bounds__(256) void final_kernel(const unsigned short* __restrict__ h,
                                                    const float* __restrict__ sums,
                                                    const float* __restrict__ gamma,
                                                    const float* __restrict__ beta,
                                                    const float* __restrict__ Wout,
                                                    const float* __restrict__ bout,
                                                    float* __restrict__ out) {
  int wid = threadIdx.x >> 6, lane = threadIdx.x & 63;
  int row = blockIdx.x * 4 + wid; // node-row (n*8+bb order)
  if (row >= TOTAL) return;
  const float inv = 1.0f / (float)TOTAL;
  float p0 = 0.f, p1 = 0.f, p2 = 0.f, p3 = 0.f;
#pragma unroll
  for (int jj = 0; jj < 2; jj++) {
    int j = lane + jj * 64;
    float mean = sums[j] * inv;
    float var = sums[128 + j] * inv - mean * mean;
    float hn = (bf2f(h[(size_t)row * HH + j]) - mean) * rsqrtf(var + 1e-5f) * gamma[j] + beta[j];
    hn = fmaxf(hn, 0.0f);
    p0 += hn * Wout[j * 4 + 0];
    p1 += hn * Wout[j * 4 + 1];
    p2 += hn * Wout[j * 4 + 2];
    p3 += hn * Wout[j * 4 + 3];
  }
  for (int off = 32; off; off >>= 1) {
    p0 += __shfl_down(p0, off);
    p1 += __shfl_down(p1, off);
    p2 += __shfl_down(p2, off);
    p3 += __shfl_down(p3, off);
  }
  if (lane == 0) {
    p0 += bout[0]; p1 += bout[1]; p2 += bout[2]; p3 += bout[3];
    float m = fmaxf(fmaxf(p0, p1), fmaxf(p2, p3));
    float e = __expf(p0 - m) + __expf(p1 - m) + __expf(p2 - m) + __expf(p3 - m);
    float lse = m + __logf(e);
    int bb = row & 7, n = row >> 3;
    float* o = out + ((size_t)bb * NN + n) * 4;
    o[0] = p0 - lse; o[1] = p1 - lse; o[2] = p2 - lse; o[3] = p3 - lse;
  }
}

// ---------------- launcher ----------------

extern "C" void kernel_launch(void* const* d_in, const int* in_sizes, int n_in,
                              void* d_out, int out_size, void* d_ws, size_t ws_size,
                              hipStream_t stream) {
  const float* x_seq = (const float*)d_in[0];
  const int* ei      = (const int*)d_in[1];
  const float* ew    = (const float*)d_in[2];
  const float* Win   = (const float*)d_in[3];
  const float* bin   = (const float*)d_in[4];
  const float* convW = (const float*)d_in[5];
  const float* convB = (const float*)d_in[6];
  const float* gamma = (const float*)d_in[7];
  const float* beta  = (const float*)d_in[8];
  const float* Wout  = (const float*)d_in[9];
  const float* bout  = (const float*)d_in[10];
  float* out = (float*)d_out;

  char* ws = (char*)d_ws;
  size_t off = 0;
  auto alloc = [&](size_t bytes) {
    void* p = ws + off;
    off += (bytes + 1023) & ~(size_t)1023;
    return p;
  };
  float* deg     = (float*)alloc(NN * 4);
  float* dis     = (float*)alloc(NN * 4);
  int*   cnt     = (int*)alloc(NN * 4);
  int*   offs    = (int*)alloc((NN + 1) * 4);
  int*   cursor  = (int*)alloc(NN * 4);
  int*   csr_src = (int*)alloc(EE * 4);
  float* csr_w   = (float*)alloc(EE * 4);
  float* sums    = (float*)alloc(256 * 4);
  unsigned short* Wp = (unsigned short*)alloc(6 * 32768 * 2);  // packed conv weights
  const size_t NH = (size_t)TOTAL * HH; // 5,120,000
  unsigned short* h0 = (unsigned short*)alloc(NH * 2);
  unsigned short* h1 = (unsigned short*)alloc(NH * 2);
  unsigned short* xt = (unsigned short*)alloc(NH * 2);
  unsigned short* rh = (unsigned short*)alloc(NH * 2);
  unsigned short* ub = (unsigned short*)alloc(NH * 2);
  unsigned short* GR = (unsigned short*)alloc(NH * 2);
  unsigned short* GU = (unsigned short*)alloc(NH * 2);
  unsigned short* Cpre = GR;  // candidate pre-scatter reuses GR

  hipMemsetAsync(deg, 0, NN * 4, stream);
  hipMemsetAsync(cnt, 0, NN * 4, stream);
  hipMemsetAsync(cursor, 0, NN * 4, stream);
  hipMemsetAsync(sums, 0, 256 * 4, stream);
  hipMemsetAsync(h0, 0, NH * 2, stream);
  hipMemsetAsync(h1, 0, NH * 2, stream);

  deg_cnt_kernel<<<(EE + 255) / 256, 256, 0, stream>>>(ei, ew, deg, cnt);
  dis_kernel<<<(NN + 255) / 256, 256, 0, stream>>>(deg, dis);
  scan_kernel<<<1, 256, 0, stream>>>(cnt, offs);
  fill_csr_kernel<<<(EE + 255) / 256, 256, 0, stream>>>(ei, ew, dis, offs, cursor, csr_src, csr_w);
  prepack_kernel<<<24576 / 256, 256, 0, stream>>>(convW, Wp);

  for (int t = 0; t < SS; t++) {
    lin_in_kernel<<<TOTAL * 32 / 256, 256, 0, stream>>>(x_seq, Win, bin, xt, t);
    for (int l = 0; l < 2; l++) {
      const unsigned short* xin = (l == 0) ? xt : h0;
      unsigned short* h = (l == 0) ? h0 : h1;
      const unsigned short* Wg = Wp + (size_t)(l * 3) * 32768;
      const unsigned short* Wc = Wp + (size_t)(l * 3 + 2) * 32768;
      const float* bRU = convB + (size_t)l * 3 * HH;
      const float* bC  = bRU + 2 * HH;
      gemm_mfma<4><<<TOTAL / 64, 256, 0, stream>>>(xin, h, Wg, GR, GU);
      scatter_gates_kernel<<<dim3(NN, 2), 256, 0, stream>>>(GR, GU, offs, csr_src, csr_w,
                                                            dis, bRU, h, rh, ub);
      gemm_mfma<2><<<TOTAL / 64, 256, 0, stream>>>(xin, rh, Wc, Cpre, Cpre);
      scatter_c_update_kernel<<<NN, 256, 0, stream>>>(Cpre, offs, csr_src, csr_w, dis, bC, ub, h);
    }
  }

  bn_stats_kernel<<<256, 256, 0, stream>>>(h1, sums);
  final_kernel<<<TOTAL / 4, 256, 0, stream>>>(h1, sums, gamma, beta, Wout, bout, out);
}